// Round 1
// 889.793 us; speedup vs baseline: 1.0020x; 1.0020x over previous
//
#include <hip/hip_runtime.h>
#include <hip/hip_fp16.h>

// LaplacianKnn:  y'[i] = a*y[i] + b * sum_j m_e * y[nbr_e],  out = dot(x, y_nu)
//   m_e = t_e/s_i, t_e = exp(-dist_e/eps)*Dinv[nbr_e], s_i = row-sum(t)
//   a = 4/eps + 2nu/k^2 + 10,  b = -4/eps
// R6: total time == (#random-gather passes) x ~230us wall; gathers are L2-hit
// and request-limited. Passes: dinv(coalesced) + fsweep + 2 sweeps.
// R7 experiment: the 237us/pass gather wall sits 4.5x above the TA floor and
// at 44% of L2 request ceiling -> hypothesis: L1 (TCP) miss handling is the
// limiter (every gather allocates+fills a 64-128B line from L2, MSHR-bound).
// Test: sc0 (L1-bypass, L2-cached) gathers in fsweep + sweep<false>;
// sweep<true> keeps the plain gather as in-bench 237us control.

typedef float __attribute__((ext_vector_type(4))) floatx4;
typedef unsigned int uint32;

static constexpr int BLOCK = 256;

// sc0 load: bypass L1, hit L2. Load + waitcnt fused in ONE asm so the
// consumer (data-dependent on %0) cannot be scheduled before the wait.
// Used only where the thread has exactly one gather in flight.
__device__ __forceinline__ float glc_load_f32(const float* p) {
  float v;
  asm volatile("global_load_dword %0, %1, off sc0\n\ts_waitcnt vmcnt(0)"
               : "=v"(v) : "v"(p) : "memory");
  return v;
}
__device__ __forceinline__ uint32 glc_load_u32(const uint32* p) {
  uint32 v;
  asm volatile("global_load_dword %0, %1, off sc0\n\ts_waitcnt vmcnt(0)"
               : "=v"(v) : "v"(p) : "memory");
  return v;
}

// ---- pass 1 (coalesced only): z4[i] = half2(1/sum_j exp(-d/eps), x[i]) ----
__global__ __launch_bounds__(256) void dinv_kernel(
    const float* __restrict__ dist, const float* __restrict__ x,
    const float* __restrict__ eps_p,
    __half2* __restrict__ z4, int n_edges) {
  int t = blockIdx.x * BLOCK + threadIdx.x;
  int e4 = t << 2;
  if (e4 >= n_edges) return;
  float inv_eps = 1.0f / eps_p[0];
  floatx4 d = __builtin_nontemporal_load((const floatx4*)(dist + e4));
  float s = __expf(-d.x * inv_eps) + __expf(-d.y * inv_eps) +
            __expf(-d.z * inv_eps) + __expf(-d.w * inv_eps);
  #pragma unroll
  for (int off = 4; off > 0; off >>= 1) s += __shfl_down(s, off, 8);
  if ((t & 7) == 0) {
    int node = t >> 3;
    z4[node] = __halves2half2(__float2half(1.0f / s), __float2half(x[node]));
  }
}

// ---- pass 2 (fused pack + sweep 1): one 4B gather/edge from 4MB z4 ----
__global__ __launch_bounds__(256) void fsweep_kernel(
    const float* __restrict__ dist, const int* __restrict__ nbr,
    const __half2* __restrict__ z4,
    const float* __restrict__ x, const float* __restrict__ eps_p,
    const float* __restrict__ k_p, const int* __restrict__ nu_p,
    uint32* __restrict__ pk, float* __restrict__ yout, int n_edges) {
  int e = blockIdx.x * BLOCK + threadIdx.x;
  if (e >= n_edges) return;
  float inv_eps = 1.0f / eps_p[0];
  int j = __builtin_nontemporal_load(nbr + e);
  float d = __builtin_nontemporal_load(dist + e);
  // sc0 gather (L1-bypass, L2-resident 4MB)
  uint32 zb = glc_load_u32(reinterpret_cast<const uint32*>(z4) + j);
  union { uint32 u; __half2 h; } cvt; cvt.u = zb;
  __half2 z = cvt.h;
  float t = __expf(-d * inv_eps) * __low2float(z);   // t_e = exp * Dinv[j]
  float g = t * __high2float(z);                     // t_e * x[j]
  float s = t;
  #pragma unroll
  for (int off = 1; off < 32; off <<= 1) s += __shfl_xor(s, off, 32);  // row sum, all lanes
  // emit packed edge for sweeps 2-3
  uint32 mq = (uint32)__float2uint_rn(t * (4096.0f / s));
  if (mq > 4095u) mq = 4095u;
  __builtin_nontemporal_store(((uint32)j << 12) | mq, pk + e);
  // y1[i] = a*x[i] + b*g/s  (leader)
  #pragma unroll
  for (int off = 16; off > 0; off >>= 1) g += __shfl_down(g, off, 32);
  if ((threadIdx.x & 31) == 0) {
    int node = e >> 5;
    float kk = k_p[0];
    float a = 4.0f * inv_eps + 2.0f * (float)nu_p[0] / (kk * kk) + 10.0f;
    float b = -4.0f * inv_eps;
    yout[node] = a * x[node] + b * g / s;   // PLAIN store: keep y hot in L2
  }
}

// ---- sweeps 2,3: 1 edge/thread, grid-stride (LAST uses 1/8 grid) ----
// A/B: sweep<false> gathers with sc0 (experiment); sweep<true> gathers plain
// (control, expected to hold ~237us).
template <bool LAST>
__global__ __launch_bounds__(256) void sweep_kernel(
    const uint32* __restrict__ pk,
    const float* __restrict__ yin, float* __restrict__ yout,
    const float* __restrict__ x,
    const float* __restrict__ eps_p, const float* __restrict__ k_p,
    const int* __restrict__ nu_p,
    float* __restrict__ out, int n_edges) {
  __shared__ float bsum;
  if (LAST) { if (threadIdx.x == 0) bsum = 0.0f; __syncthreads(); }
  float inv_eps = 1.0f / eps_p[0];
  float kk = k_p[0];
  float a  = 4.0f * inv_eps + 2.0f * (float)nu_p[0] / (kk * kk) + 10.0f;
  float bq = -4.0f * inv_eps * (1.0f / 4096.0f);
  int stride = gridDim.x * BLOCK;
  for (int e = blockIdx.x * BLOCK + threadIdx.x; e < n_edges; e += stride) {
    uint32 p = __builtin_nontemporal_load(pk + e);   // single 4B stream load/edge
    float yv;
    if (LAST) yv = yin[p >> 12];                     // PLAIN gather (control)
    else      yv = glc_load_f32(yin + (p >> 12));    // sc0 gather (experiment)
    float g = (float)(p & 0xFFFu) * yv;
    #pragma unroll
    for (int off = 16; off > 0; off >>= 1) g += __shfl_down(g, off, 32);
    if ((threadIdx.x & 31) == 0) {
      int node = e >> 5;
      float ynew = a * yin[node] + bq * g;
      if (LAST) atomicAdd(&bsum, x[node] * ynew);
      else yout[node] = ynew;        // PLAIN store: keep y hot in L2
    }
  }
  if (LAST) { __syncthreads(); if (threadIdx.x == 0) atomicAdd(out, bsum); }
}

extern "C" void kernel_launch(void* const* d_in, const int* in_sizes, int n_in,
                              void* d_out, int out_size, void* d_ws, size_t ws_size,
                              hipStream_t stream) {
  const float* x     = (const float*)d_in[0];
  const int*   nbr   = (const int*)d_in[1];
  const float* dist  = (const float*)d_in[2];
  const float* eps_p = (const float*)d_in[3];
  const float* k_p   = (const float*)d_in[4];
  const int*   nu_p  = (const int*)d_in[5];
  float* out = (float*)d_out;

  int n  = in_sizes[0];   // 1,000,000 nodes  (< 2^20 -> 20-bit index fits)
  int ne = in_sizes[1];   // 32,000,000 edges

  uint32* pk   = (uint32*)d_ws;         // [ne]  packed edges
  __half2* z4  = (__half2*)(pk + ne);   // [n]   (Dinv, x) in f16
  float* y1    = (float*)(z4 + n);      // [n]
  float* y2    = y1 + n;                // [n]

  (void)hipMemsetAsync(d_out, 0, sizeof(float), stream);

  int gridE = (ne + BLOCK - 1) / BLOCK;            // 1 edge/thread
  int grid4 = (ne + BLOCK * 4 - 1) / (BLOCK * 4);  // 4 edges/thread
  dinv_kernel<<<grid4, BLOCK, 0, stream>>>(dist, x, eps_p, z4, ne);
  fsweep_kernel<<<gridE, BLOCK, 0, stream>>>(dist, nbr, z4, x, eps_p, k_p, nu_p, pk, y1, ne);
  sweep_kernel<false><<<gridE, BLOCK, 0, stream>>>(pk, y1, y2, x, eps_p, k_p, nu_p, out, ne);
  sweep_kernel<true ><<<gridE / 8, BLOCK, 0, stream>>>(pk, y2, nullptr, x, eps_p, k_p, nu_p, out, ne);
}